// Round 16
// baseline (201.560 us; speedup 1.0000x reference)
//
#include <hip/hip_runtime.h>
#include <hip/hip_bf16.h>
#include <stdint.h>

// Problem constants
#define BB 4
#define SS 2048
#define CC 1024
#define HH 16
#define DD 64
#define MTOT (BB*SS)      // 8192
#define NQKV 3072

typedef __attribute__((ext_vector_type(8))) short short8;    // 8 bf16 (4 VGPRs)
typedef __attribute__((ext_vector_type(4))) float f32x4;     // 16x16 MFMA accumulator
typedef __attribute__((ext_vector_type(16))) float f32x16;   // 32x32 MFMA accumulator
typedef __attribute__((ext_vector_type(4))) unsigned uint4v;
typedef __attribute__((ext_vector_type(2))) unsigned uint2v;

#define MFMA16(A,B,C) __builtin_amdgcn_mfma_f32_16x16x32_bf16((A),(B),(C),0,0,0)
#define MFMA32(A,B,C) __builtin_amdgcn_mfma_f32_32x32x16_bf16((A),(B),(C),0,0,0)
#define BARRIER() asm volatile("s_barrier" ::: "memory")

__device__ __forceinline__ ushort f2bf(float f) {
  uint32_t u = __builtin_bit_cast(uint32_t, f);
  u += 0x7FFFu + ((u >> 16) & 1u);   // round-to-nearest-even
  return (ushort)(u >> 16);
}

__device__ __forceinline__ float bf2f(ushort u) {
  return __builtin_bit_cast(float, (uint32_t)u << 16);
}

__device__ __forceinline__ unsigned cvtpk(float lo, float hi) {
  unsigned r;
  asm("v_cvt_pk_bf16_f32 %0, %1, %2" : "=v"(r) : "v"(lo), "v"(hi));
  return r;
}

__device__ __forceinline__ float hw_exp2(float x) {
  float r;
  asm("v_exp_f32 %0, %1" : "=v"(r) : "v"(x));
  return r;
}

__device__ __forceinline__ f32x16 zero16() {
  f32x16 v;
  #pragma unroll
  for (int i = 0; i < 16; ++i) v[i] = 0.f;
  return v;
}

// ---------------- merged f32 -> bf16 conversion (x, W_qkv, W_out in one launch) ------------
__global__ void cvt3_kernel(const float* __restrict__ a, ushort* __restrict__ da, int na4,
                            const float* __restrict__ b, ushort* __restrict__ db, int nb4,
                            const float* __restrict__ c, ushort* __restrict__ dc, int nc4) {
  int total = na4 + nb4 + nc4;
  int stride = gridDim.x * blockDim.x;
  for (int i = blockIdx.x * blockDim.x + threadIdx.x; i < total; i += stride) {
    const float4* s; ushort4* d; int k;
    if (i < na4)            { s = (const float4*)a; d = (ushort4*)da; k = i; }
    else if (i < na4 + nb4) { s = (const float4*)b; d = (ushort4*)db; k = i - na4; }
    else                    { s = (const float4*)c; d = (ushort4*)dc; k = i - na4 - nb4; }
    float4 v = s[k];
    ushort4 o;
    o.x = f2bf(v.x); o.y = f2bf(v.y); o.z = f2bf(v.z); o.w = f2bf(v.w);
    d[k] = o;
  }
}

// ======== GEMM core: 128x128 tile, BK=64, 4 waves, dbuf LDS 64KB, counted vmcnt ========
__device__ __forceinline__ void stage_half128(const ushort* __restrict__ gsrc, ushort* ldsbase, int tid) {
  #pragma unroll
  for (int ld = 0; ld < 4; ++ld) {
    int ci = ld * 256 + tid;                  // 16B chunk 0..1023 (128 rows x 8 slots)
    int row = ci >> 3, slot = ci & 7;
    const ushort* src = gsrc + (size_t)row * 1024 + ((slot ^ (row & 7)) << 3);
    __builtin_amdgcn_global_load_lds(
        (const __attribute__((address_space(1))) uint32_t*)src,
        (__attribute__((address_space(3))) uint32_t*)(ldsbase + ci * 8), 16, 0, 0);
  }
}

__device__ __forceinline__ short8 rd_frag(const ushort* Lb, int row, int slot) {
  return *(const short8*)(Lb + row * 64 + ((slot ^ (row & 7)) << 3));
}

__device__ __forceinline__ void core128(const ushort* __restrict__ A, const ushort* __restrict__ Bw,
                                        int m0, int n0, ushort* L, f32x4 acc[4][4]) {
  const int tid = threadIdx.x, lane = tid & 63, w = tid >> 6;
  const int q = lane & 15, g = lane >> 4;
  const int wm = (w >> 1) * 64, wn = (w & 1) * 64;
  const ushort* Ag = A + (size_t)m0 * 1024;
  const ushort* Bg = Bw + (size_t)n0 * 1024;

  #pragma unroll
  for (int tt = 0; tt < 2; ++tt) {
    stage_half128(Ag + tt * 64, L + tt * 16384, tid);
    stage_half128(Bg + tt * 64, L + tt * 16384 + 8192, tid);
  }
  asm volatile("s_waitcnt vmcnt(8)" ::: "memory");   // tile 0 landed (tile 1 in flight)
  BARRIER();

  #pragma unroll 1
  for (int t = 0; t < 16; ++t) {
    const ushort* La = L + (t & 1) * 16384;
    const ushort* Lb = La + 8192;
    short8 af[4][2], bf[4][2];
    #pragma unroll
    for (int mi = 0; mi < 4; ++mi)
      #pragma unroll
      for (int ks = 0; ks < 2; ++ks)
        af[mi][ks] = rd_frag(La, wm + mi * 16 + q, ks * 4 + g);
    #pragma unroll
    for (int nj = 0; nj < 4; ++nj)
      #pragma unroll
      for (int ks = 0; ks < 2; ++ks)
        bf[nj][ks] = rd_frag(Lb, wn + nj * 16 + q, ks * 4 + g);
    #pragma unroll
    for (int mi = 0; mi < 4; ++mi)
      #pragma unroll
      for (int nj = 0; nj < 4; ++nj) {
        acc[mi][nj] = MFMA16(af[mi][0], bf[nj][0], acc[mi][nj]);
        acc[mi][nj] = MFMA16(af[mi][1], bf[nj][1], acc[mi][nj]);
      }
    BARRIER();                                      // all waves done reading buf (t&1)
    if (t <= 13) {
      ushort* Ls = L + (t & 1) * 16384;             // overwrite-safe: last read barrier'd above
      stage_half128(Ag + (t + 2) * 64, Ls, tid);
      stage_half128(Bg + (t + 2) * 64, Ls + 8192, tid);
      asm volatile("s_waitcnt vmcnt(8)" ::: "memory");  // tile t+1 landed; t+2's 8 in flight
      BARRIER();
    } else if (t == 14) {
      asm volatile("s_waitcnt vmcnt(0)" ::: "memory");  // tile 15 landed
      BARRIER();
    }
  }
}

// ---------------- GEMM1: qkv = x @ W_qkv^T, LDS-restaged coalesced scatter ----------------
// QF/KF layout: element (s,c) at (((bh*128 + (s>>4))*2 + (c>>5))*64 + ((c>>3)&3)*16 + (s&15))*8 + (c&7)
// VF layout:    element (s,c) at (((bh*64 + (s>>5))*4 + (c>>4))*64 + ((s>>3)&3)*16 + (c&15))*8 + (s&7)
__global__ __launch_bounds__(256, 2) void gemm_qkv(const ushort* __restrict__ xb, const ushort* __restrict__ wqkv,
                                                   ushort* __restrict__ qfbuf, ushort* __restrict__ kfbuf,
                                                   ushort* __restrict__ vfbuf) {
  __shared__ __align__(16) ushort L[32768];   // 64 KB -> 2 blocks/CU
  const int bid = blockIdx.x;                 // 1536 = 8 XCD * (64 m * 3 n); n fastest per XCD
  const int xcd = bid & 7, r0 = bid >> 3;
  const int m0 = (r0 / 3) * 128, n0 = (xcd * 3 + (r0 % 3)) * 128;

  f32x4 acc[4][4];
  #pragma unroll
  for (int i = 0; i < 4; ++i)
    #pragma unroll
    for (int j = 0; j < 4; ++j) acc[i][j] = f32x4{0.f, 0.f, 0.f, 0.f};
  core128(xb, wqkv, m0, n0, L, acc);

  const int lane = threadIdx.x & 63, wave = threadIdx.x >> 6;
  const int g = lane >> 4, q = lane & 15;
  const int wm = (wave >> 1) * 64, wn = (wave & 1) * 64;
  const int s0 = m0 & 2047, bb = m0 >> 11;

  // ---- write phase: C/D (col=q, row=g*4+r) -> LDS [mr][nc ^ ((mr&7)<<4)], bf16
  #pragma unroll
  for (int j = 0; j < 4; ++j) {
    int n = n0 + wn + j * 16 + q;
    int h = n / 192;
    int which = (n - h * 192) >> 6;
    float scl = (which == 0) ? 0.045084222f : 1.0f;   // 1/sqrt(C)*log2(e) folded into Q
    int nc = wn + j * 16 + q;
    #pragma unroll
    for (int i = 0; i < 4; ++i) {
      #pragma unroll
      for (int rr = 0; rr < 4; ++rr) {
        int mr = wm + i * 16 + g * 4 + rr;
        L[mr * 128 + (nc ^ ((mr & 7) << 4))] = f2bf(acc[i][j][rr] * scl);
      }
    }
  }
  __syncthreads();

  // ---- read+store phase: wave w owns n-octet-group [n0+32w, +32) (which/h wave-uniform)
  {
    const int n_g = n0 + wave * 32;
    const int h = n_g / 192, rem = n_g - h * 192, which = rem >> 6;
    const int bh = bb * 16 + h;
    if (which < 2) {
      ushort* dst0 = (which == 0) ? qfbuf : kfbuf;
      const int c0 = (rem & 63) >> 5;
      #pragma unroll
      for (int k = 0; k < 8; ++k) {
        int jt = (s0 >> 4) + k;
        int mr = k * 16 + (lane & 15);
        int nc0 = wave * 32 + (lane >> 4) * 8;
        short8 v = *(const short8*)(L + mr * 128 + (nc0 ^ ((mr & 7) << 4)));
        *(short8*)(dst0 + ((((size_t)bh * 128 + jt) * 2 + c0) * 64 + lane) * 8) = v;
      }
    } else {
      const int ct0 = (rem & 63) >> 4;
      #pragma unroll
      for (int k = 0; k < 8; ++k) {
        int jcr = k >> 1, ct = ct0 + (k & 1);
        int nc = wave * 32 + (k & 1) * 16 + (lane & 15);
        int mrb = jcr * 32 + (lane >> 4) * 8;
        short8 v;
        #pragma unroll
        for (int e = 0; e < 8; ++e) {
          int mr = mrb + e;
          v[e] = (short)L[mr * 128 + (nc ^ ((mr & 7) << 4))];
        }
        int jc = (s0 >> 5) + jcr;
        *(short8*)(vfbuf + ((((size_t)bh * 64 + jc) * 4 + ct) * 64 + lane) * 8) = v;
      }
    }
  }
}

// ---------------- GEMM2: out = attn_out @ W_out^T + b_out + x (f32 out, coalesced) --------
__global__ __launch_bounds__(256, 2) void gemm_out(const ushort* __restrict__ ab, const ushort* __restrict__ wout,
                                                   const ushort* __restrict__ xbb, const float* __restrict__ bias,
                                                   float* __restrict__ out) {
  __shared__ __align__(16) ushort L[32768];
  const int bid = blockIdx.x;                 // 512 = 8 * 64 ; 1 n-panel per XCD
  const int sw = (bid & 7) * 64 + (bid >> 3);
  const int m0 = (sw & 63) * 128, n0 = (sw >> 6) * 128;

  f32x4 acc[4][4];
  #pragma unroll
  for (int i = 0; i < 4; ++i)
    #pragma unroll
    for (int j = 0; j < 4; ++j) acc[i][j] = f32x4{0.f, 0.f, 0.f, 0.f};
  core128(ab, wout, m0, n0, L, acc);

  const int tid = threadIdx.x;
  const int lane = tid & 63, wave = tid >> 6;
  const int g = lane >> 4, q = lane & 15;
  const int wm = (wave >> 1) * 64, wn = (wave & 1) * 64;
  float* Lf = reinterpret_cast<float*>(L);    // 128x128 f32 = 64KB (core128 ended barrier'd)

  // write phase: swz col' = col ^ (bit2(row)<<2) ^ (bit3(row)<<4): 2-way max, float4-safe
  #pragma unroll
  for (int j = 0; j < 4; ++j) {
    int nc = wn + j * 16 + q;
    #pragma unroll
    for (int i = 0; i < 4; ++i) {
      #pragma unroll
      for (int rr = 0; rr < 4; ++rr) {
        int mr = wm + i * 16 + g * 4 + rr;
        int swz = ((mr & 4) << 0) | ((mr & 8) << 1);   // bits {2,4}
        Lf[mr * 128 + (nc ^ swz)] = acc[i][j][rr];
      }
    }
  }
  __syncthreads();

  // read+store phase: fully coalesced float4 stores + bf16 residual + bias
  #pragma unroll
  for (int k = 0; k < 16; ++k) {
    int ci = k * 256 + tid;          // 0..4095 = 128 rows x 32 col-chunks
    int row = ci >> 5, cb = (ci & 31) * 4;
    int swz = ((row & 4) << 0) | ((row & 8) << 1);
    float4 v = *(const float4*)(Lf + row * 128 + (cb ^ swz));
    size_t m = (size_t)(m0 + row);
    int n = n0 + cb;
    ushort4 xr = *(const ushort4*)(xbb + m * 1024 + n);
    float4 bv = *(const float4*)(bias + n);
    float4 o;
    o.x = v.x + bv.x + bf2f(xr.x);
    o.y = v.y + bv.y + bf2f(xr.y);
    o.z = v.z + bv.z + bf2f(xr.z);
    o.w = v.w + bv.w + bf2f(xr.w);
    *(float4*)(out + m * 1024 + n) = o;
  }
}

// ---------------- Flash attention v10: v9 primitives + 2-tile ILP (64 q-rows/wave) ----------
// 2 q-tiles of 32 rows per wave, KVBLK=32 (two chunks per iter), zero LDS.
// Swapped S^T = mfma32(K,Q); P redistribution via v_permlane32_swap; l via ones-MFMA.
__device__ __forceinline__ f32x16 qk32(const short8 kf[4], const short8 qf[4]) {
  f32x16 sa = zero16();
  __builtin_amdgcn_s_setprio(1);
  #pragma unroll
  for (int kc = 0; kc < 4; ++kc) sa = MFMA32(kf[kc], qf[kc], sa);
  __builtin_amdgcn_s_setprio(0);
  return sa;
}

__device__ __forceinline__ void exppv32(const f32x16& sa, const short8 vf[2][2],
                                        const short8 onesf, f32x16& oa0, f32x16& oa1, f32x16& la) {
  unsigned w[8];
  #pragma unroll
  for (int i = 0; i < 8; ++i)
    w[i] = cvtpk(hw_exp2(sa[2 * i]), hw_exp2(sa[2 * i + 1]));
  #pragma unroll
  for (int kj = 0; kj < 2; ++kj) {
    uint2v p0 = __builtin_amdgcn_permlane32_swap(w[kj * 4 + 2], w[kj * 4 + 0], false, false);
    uint2v p1 = __builtin_amdgcn_permlane32_swap(w[kj * 4 + 3], w[kj * 4 + 1], false, false);
    uint4v t;
    t.x = p0[1]; t.y = p1[1]; t.z = p0[0]; t.w = p1[0];
    short8 pa = __builtin_bit_cast(short8, t);
    __builtin_amdgcn_s_setprio(1);
    oa0 = MFMA32(pa, vf[kj][0], oa0);
    oa1 = MFMA32(pa, vf[kj][1], oa1);
    la  = MFMA32(pa, onesf, la);
    __builtin_amdgcn_s_setprio(0);
  }
}

__global__ __launch_bounds__(256) void attn_kernel(const ushort* __restrict__ QF, const ushort* __restrict__ KF,
                                                   const ushort* __restrict__ VF, ushort* __restrict__ aout) {
  const int bid = blockIdx.x;                 // 512: per XCD (bid&7), qb cycles fastest
  const int xcd = bid & 7, r = bid >> 3;      // r 0..63
  const int qb = r & 7, bh = xcd + (r >> 3) * 8;
  const int lane = threadIdx.x & 63, wave = threadIdx.x >> 6;
  const int l31 = lane & 31, hi = lane >> 5, l15 = lane & 15, l31h = l31 >> 4;
  const int qt0 = qb * 8 + wave * 2;          // first 32-row q-tile (0..63), wave owns qt0,qt0+1

  const ushort* QFb = QF + (size_t)bh * 131072;
  const ushort* KFb = KF + (size_t)bh * 131072;
  const ushort* VFb = VF + (size_t)bh * 131072;

  short8 onesf;                               // B-frag of 1.0 for l row-sums
  #pragma unroll
  for (int e = 0; e < 8; ++e) onesf[e] = (short)0x3F80;

  // Q B-frags per tile (q = qt*32 + l31, c = kc*16 + hi*8 + e)
  short8 qf[2][4];
  #pragma unroll
  for (int t = 0; t < 2; ++t)
    #pragma unroll
    for (int kc = 0; kc < 4; ++kc) {
      int jt16 = (qt0 + t) * 2 + l31h;
      int lane2 = (((kc * 2 + hi) & 3) << 4) + l15;
      qf[t][kc] = *(const short8*)(QFb + ((size_t)(jt16 * 2 + (kc >> 1)) * 64 + lane2) * 8);
    }

  f32x16 oa00 = zero16(), oa01 = zero16(), la0 = zero16();
  f32x16 oa10 = zero16(), oa11 = zero16(), la1 = zero16();

  short8 kfA[4], kfB[4], vfA[2][2], vfB[2][2];
  #pragma unroll
  for (int kc = 0; kc < 4; ++kc) {
    int lane2 = (((kc * 2 + hi) & 3) << 4) + l15;
    kfA[kc] = *(const short8*)(KFb + ((size_t)(l31h * 2 + (kc >> 1)) * 64 + lane2) * 8);
  }

  #pragma unroll 1
  for (int j0 = 0; j0 < SS; j0 += 64) {
    // V frags chunk j0; K prefetch chunk j0+32
    #pragma unroll
    for (int kj = 0; kj < 2; ++kj)
      #pragma unroll
      for (int cb = 0; cb < 2; ++cb) {
        int ct = cb * 2 + l31h;
        int lane16 = (((kj * 2 + hi) & 3) << 4) + l15;
        vfA[kj][cb] = *(const short8*)(VFb + ((size_t)((j0 >> 5) * 4 + ct) * 64 + lane16) * 8);
      }
    #pragma unroll
    for (int kc = 0; kc < 4; ++kc) {
      int jt16 = ((j0 + 32) >> 4) + l31h;
      int lane2 = (((kc * 2 + hi) & 3) << 4) + l15;
      kfB[kc] = *(const short8*)(KFb + ((size_t)(jt16 * 2 + (kc >> 1)) * 64 + lane2) * 8);
    }

    {  // chunk A: both tiles' QK first (independent MFMA), then exp/PV per tile
      f32x16 sa0 = qk32(kfA, qf[0]);
      f32x16 sa1 = qk32(kfA, qf[1]);
      exppv32(sa0, vfA, onesf, oa00, oa01, la0);
      exppv32(sa1, vfA, onesf, oa10, oa11, la1);
    }

    // V frags chunk j0+32; K prefetch chunk j0+64
    #pragma unroll
    for (int kj = 0; kj < 2; ++kj)
      #pragma unroll
      for (int cb = 0; cb < 2; ++cb) {
        int ct = cb * 2 + l31h;
        int lane16 = (((kj * 2 + hi) & 3) << 4) + l15;
        vfB[kj][cb] = *(const short8*)(VFb + ((size_t)(((j0 + 32) >> 5) * 4 + ct) * 64 + lane16) * 8);
      }
    if (j0 + 64 < SS) {
      #pragma unroll
      for (int kc = 0; kc < 4; ++kc) {
        int jt16 = ((j0 + 64) >> 4) + l31h;
        int lane2 = (((kc * 2 + hi) & 3) << 4) + l15;
        kfA[kc] = *(const short8*)(KFb + ((size_t)(jt16 * 2 + (kc >> 1)) * 64 + lane2) * 8);
      }
    }

    {  // chunk B
      f32x16 sa0 = qk32(kfB, qf[0]);
      f32x16 sa1 = qk32(kfB, qf[1]);
      exppv32(sa0, vfB, onesf, oa00, oa01, la0);
      exppv32(sa1, vfB, onesf, oa10, oa11, la1);
    }
  }

  // epilogue: O col = l31, row q = tile*32 + (r&3)+8*(r>>2)+4*hi; la same rows
  const int b = bh >> 4, h = bh & 15;
  #pragma unroll
  for (int r16 = 0; r16 < 16; ++r16) {
    int rowoff = (r16 & 3) + 8 * (r16 >> 2) + 4 * hi;
    {
      float inv = 1.0f / la0[r16];
      size_t base = ((size_t)b * SS + qt0 * 32 + rowoff) * CC + h * DD;
      aout[base + l31]      = f2bf(oa00[r16] * inv);
      aout[base + 32 + l31] = f2bf(oa01[r16] * inv);
    }
    {
      float inv = 1.0f / la1[r16];
      size_t base = ((size_t)b * SS + (qt0 + 1) * 32 + rowoff) * CC + h * DD;
      aout[base + l31]      = f2bf(oa10[r16] * inv);
      aout[base + 32 + l31] = f2bf(oa11[r16] * inv);
    }
  }
}

extern "C" void kernel_launch(void* const* d_in, const int* in_sizes, int n_in,
                              void* d_out, int out_size, void* d_ws, size_t ws_size,
                              hipStream_t stream) {
  const float* x    = (const float*)d_in[0];   // [4,2048,1024]
  const float* wqkv = (const float*)d_in[1];   // [3072,1024]
  const float* wout = (const float*)d_in[2];   // [1024,1024]
  const float* bias = (const float*)d_in[3];   // [1024]
  float* out = (float*)d_out;

  // workspace carve (ushort elements), total 44M elems = 88MB
  ushort* xb    = (ushort*)d_ws;                   // 8M
  ushort* wqkvb = xb + (size_t)8 * 1024 * 1024;    // 3M
  ushort* woutb = wqkvb + (size_t)3 * 1024 * 1024; // 1M
  ushort* qfbuf = woutb + (size_t)1024 * 1024;     // 8M
  ushort* kfbuf = qfbuf + (size_t)8 * 1024 * 1024; // 8M
  ushort* vfbuf = kfbuf + (size_t)8 * 1024 * 1024; // 8M
  ushort* aout  = vfbuf + (size_t)8 * 1024 * 1024; // 8M

  hipLaunchKernelGGL(cvt3_kernel, dim3(2048), dim3(256), 0, stream,
                     x, xb, 8 * 1024 * 1024 / 4,
                     wqkv, wqkvb, 3 * 1024 * 1024 / 4,
                     wout, woutb, 1024 * 1024 / 4);

  hipLaunchKernelGGL(gemm_qkv, dim3(1536), dim3(256), 0, stream,
                     xb, wqkvb, qfbuf, kfbuf, vfbuf);
  hipLaunchKernelGGL(attn_kernel, dim3(512), dim3(256), 0, stream,
                     qfbuf, kfbuf, vfbuf, aout);
  hipLaunchKernelGGL(gemm_out, dim3(512), dim3(256), 0, stream,
                     aout, woutb, xb, bias, out);
}

// Round 17
// 189.860 us; speedup vs baseline: 1.0616x; 1.0616x over previous
//
#include <hip/hip_runtime.h>
#include <hip/hip_bf16.h>
#include <stdint.h>

// Problem constants
#define BB 4
#define SS 2048
#define CC 1024
#define HH 16
#define DD 64
#define MTOT (BB*SS)      // 8192
#define NQKV 3072

typedef __attribute__((ext_vector_type(8))) short short8;   // 8 bf16 (4 VGPRs)
typedef __attribute__((ext_vector_type(4))) float f32x4;    // MFMA accumulator

#define MFMA16(A,B,C) __builtin_amdgcn_mfma_f32_16x16x32_bf16((A),(B),(C),0,0,0)
#define BARRIER() asm volatile("s_barrier" ::: "memory")

__device__ __forceinline__ ushort f2bf(float f) {
  uint32_t u = __builtin_bit_cast(uint32_t, f);
  u += 0x7FFFu + ((u >> 16) & 1u);   // round-to-nearest-even
  return (ushort)(u >> 16);
}

__device__ __forceinline__ float bf2f(ushort u) {
  return __builtin_bit_cast(float, (uint32_t)u << 16);
}

__device__ __forceinline__ unsigned cvtpk(float lo, float hi) {
  unsigned r;
  asm("v_cvt_pk_bf16_f32 %0, %1, %2" : "=v"(r) : "v"(lo), "v"(hi));
  return r;
}

__device__ __forceinline__ float hw_exp2(float x) {
  float r;
  asm("v_exp_f32 %0, %1" : "=v"(r) : "v"(x));
  return r;
}

// ---------------- merged f32 -> bf16 conversion (x, W_qkv, W_out in one launch) ------------
__global__ void cvt3_kernel(const float* __restrict__ a, ushort* __restrict__ da, int na4,
                            const float* __restrict__ b, ushort* __restrict__ db, int nb4,
                            const float* __restrict__ c, ushort* __restrict__ dc, int nc4) {
  int total = na4 + nb4 + nc4;
  int stride = gridDim.x * blockDim.x;
  for (int i = blockIdx.x * blockDim.x + threadIdx.x; i < total; i += stride) {
    const float4* s; ushort4* d; int k;
    if (i < na4)            { s = (const float4*)a; d = (ushort4*)da; k = i; }
    else if (i < na4 + nb4) { s = (const float4*)b; d = (ushort4*)db; k = i - na4; }
    else                    { s = (const float4*)c; d = (ushort4*)dc; k = i - na4 - nb4; }
    float4 v = s[k];
    ushort4 o;
    o.x = f2bf(v.x); o.y = f2bf(v.y); o.z = f2bf(v.z); o.w = f2bf(v.w);
    d[k] = o;
  }
}

// ======== GEMM core: 128x128 tile, BK=64, 4 waves, dbuf LDS 64KB, counted vmcnt ========
__device__ __forceinline__ void stage_half128(const ushort* __restrict__ gsrc, ushort* ldsbase, int tid) {
  #pragma unroll
  for (int ld = 0; ld < 4; ++ld) {
    int ci = ld * 256 + tid;                  // 16B chunk 0..1023 (128 rows x 8 slots)
    int row = ci >> 3, slot = ci & 7;
    const ushort* src = gsrc + (size_t)row * 1024 + ((slot ^ (row & 7)) << 3);
    __builtin_amdgcn_global_load_lds(
        (const __attribute__((address_space(1))) uint32_t*)src,
        (__attribute__((address_space(3))) uint32_t*)(ldsbase + ci * 8), 16, 0, 0);
  }
}

__device__ __forceinline__ short8 rd_frag(const ushort* Lb, int row, int slot) {
  return *(const short8*)(Lb + row * 64 + ((slot ^ (row & 7)) << 3));
}

__device__ __forceinline__ void core128(const ushort* __restrict__ A, const ushort* __restrict__ Bw,
                                        int m0, int n0, ushort* L, f32x4 acc[4][4]) {
  const int tid = threadIdx.x, lane = tid & 63, w = tid >> 6;
  const int q = lane & 15, g = lane >> 4;
  const int wm = (w >> 1) * 64, wn = (w & 1) * 64;
  const ushort* Ag = A + (size_t)m0 * 1024;
  const ushort* Bg = Bw + (size_t)n0 * 1024;

  #pragma unroll
  for (int tt = 0; tt < 2; ++tt) {
    stage_half128(Ag + tt * 64, L + tt * 16384, tid);
    stage_half128(Bg + tt * 64, L + tt * 16384 + 8192, tid);
  }
  asm volatile("s_waitcnt vmcnt(8)" ::: "memory");   // tile 0 landed (tile 1 in flight)
  BARRIER();

  #pragma unroll 1
  for (int t = 0; t < 16; ++t) {
    const ushort* La = L + (t & 1) * 16384;
    const ushort* Lb = La + 8192;
    short8 af[4][2], bf[4][2];
    #pragma unroll
    for (int mi = 0; mi < 4; ++mi)
      #pragma unroll
      for (int ks = 0; ks < 2; ++ks)
        af[mi][ks] = rd_frag(La, wm + mi * 16 + q, ks * 4 + g);
    #pragma unroll
    for (int nj = 0; nj < 4; ++nj)
      #pragma unroll
      for (int ks = 0; ks < 2; ++ks)
        bf[nj][ks] = rd_frag(Lb, wn + nj * 16 + q, ks * 4 + g);
    #pragma unroll
    for (int mi = 0; mi < 4; ++mi)
      #pragma unroll
      for (int nj = 0; nj < 4; ++nj) {
        acc[mi][nj] = MFMA16(af[mi][0], bf[nj][0], acc[mi][nj]);
        acc[mi][nj] = MFMA16(af[mi][1], bf[nj][1], acc[mi][nj]);
      }
    BARRIER();                                      // all waves done reading buf (t&1)
    if (t <= 13) {
      ushort* Ls = L + (t & 1) * 16384;             // overwrite-safe: last read barrier'd above
      stage_half128(Ag + (t + 2) * 64, Ls, tid);
      stage_half128(Bg + (t + 2) * 64, Ls + 8192, tid);
      asm volatile("s_waitcnt vmcnt(8)" ::: "memory");  // tile t+1 landed; t+2's 8 in flight
      BARRIER();
    } else if (t == 14) {
      asm volatile("s_waitcnt vmcnt(0)" ::: "memory");  // tile 15 landed
      BARRIER();
    }
  }
}

// ---------------- GEMM1: qkv = x @ W_qkv^T, LDS-restaged coalesced scatter ----------------
// QF/KF layout: element (s,c) at (((bh*128 + (s>>4))*2 + (c>>5))*64 + ((c>>3)&3)*16 + (s&15))*8 + (c&7)
// VF layout:    element (s,c) at (((bh*64 + (s>>5))*4 + (c>>4))*64 + ((s>>3)&3)*16 + (c&15))*8 + (s&7)
__global__ __launch_bounds__(256, 2) void gemm_qkv(const ushort* __restrict__ xb, const ushort* __restrict__ wqkv,
                                                   ushort* __restrict__ qfbuf, ushort* __restrict__ kfbuf,
                                                   ushort* __restrict__ vfbuf) {
  __shared__ __align__(16) ushort L[32768];   // 64 KB -> 2 blocks/CU
  const int bid = blockIdx.x;                 // 1536 = 8 XCD * (64 m * 3 n); n fastest per XCD
  const int xcd = bid & 7, r0 = bid >> 3;
  const int m0 = (r0 / 3) * 128, n0 = (xcd * 3 + (r0 % 3)) * 128;

  f32x4 acc[4][4];
  #pragma unroll
  for (int i = 0; i < 4; ++i)
    #pragma unroll
    for (int j = 0; j < 4; ++j) acc[i][j] = f32x4{0.f, 0.f, 0.f, 0.f};
  core128(xb, wqkv, m0, n0, L, acc);

  const int lane = threadIdx.x & 63, wave = threadIdx.x >> 6;
  const int g = lane >> 4, q = lane & 15;
  const int wm = (wave >> 1) * 64, wn = (wave & 1) * 64;
  const int s0 = m0 & 2047, bb = m0 >> 11;

  // ---- write phase: C/D (col=q, row=g*4+r) -> LDS [mr][nc ^ ((mr&7)<<4)], bf16
  #pragma unroll
  for (int j = 0; j < 4; ++j) {
    int n = n0 + wn + j * 16 + q;
    int h = n / 192;
    int which = (n - h * 192) >> 6;
    float scl = (which == 0) ? 0.045084222f : 1.0f;   // 1/sqrt(C)*log2(e) folded into Q
    int nc = wn + j * 16 + q;
    #pragma unroll
    for (int i = 0; i < 4; ++i) {
      #pragma unroll
      for (int rr = 0; rr < 4; ++rr) {
        int mr = wm + i * 16 + g * 4 + rr;
        L[mr * 128 + (nc ^ ((mr & 7) << 4))] = f2bf(acc[i][j][rr] * scl);
      }
    }
  }
  __syncthreads();

  // ---- read+store phase: wave w owns n-octet-group [n0+32w, +32) (which/h wave-uniform)
  {
    const int n_g = n0 + wave * 32;
    const int h = n_g / 192, rem = n_g - h * 192, which = rem >> 6;
    const int bh = bb * 16 + h;
    if (which < 2) {
      ushort* dst0 = (which == 0) ? qfbuf : kfbuf;
      const int c0 = (rem & 63) >> 5;
      #pragma unroll
      for (int k = 0; k < 8; ++k) {
        int jt = (s0 >> 4) + k;
        int mr = k * 16 + (lane & 15);
        int nc0 = wave * 32 + (lane >> 4) * 8;
        short8 v = *(const short8*)(L + mr * 128 + (nc0 ^ ((mr & 7) << 4)));
        *(short8*)(dst0 + ((((size_t)bh * 128 + jt) * 2 + c0) * 64 + lane) * 8) = v;
      }
    } else {
      const int ct0 = (rem & 63) >> 4;
      #pragma unroll
      for (int k = 0; k < 8; ++k) {
        int jcr = k >> 1, ct = ct0 + (k & 1);
        int nc = wave * 32 + (k & 1) * 16 + (lane & 15);
        int mrb = jcr * 32 + (lane >> 4) * 8;
        short8 v;
        #pragma unroll
        for (int e = 0; e < 8; ++e) {
          int mr = mrb + e;
          v[e] = (short)L[mr * 128 + (nc ^ ((mr & 7) << 4))];
        }
        int jc = (s0 >> 5) + jcr;
        *(short8*)(vfbuf + ((((size_t)bh * 64 + jc) * 4 + ct) * 64 + lane) * 8) = v;
      }
    }
  }
}

// ---------------- GEMM2: out = attn_out @ W_out^T + b_out + x (f32 out, coalesced) --------
__global__ __launch_bounds__(256, 2) void gemm_out(const ushort* __restrict__ ab, const ushort* __restrict__ wout,
                                                   const ushort* __restrict__ xbb, const float* __restrict__ bias,
                                                   float* __restrict__ out) {
  __shared__ __align__(16) ushort L[32768];
  const int bid = blockIdx.x;                 // 512 = 8 * 64 ; 1 n-panel per XCD
  const int sw = (bid & 7) * 64 + (bid >> 3);
  const int m0 = (sw & 63) * 128, n0 = (sw >> 6) * 128;

  f32x4 acc[4][4];
  #pragma unroll
  for (int i = 0; i < 4; ++i)
    #pragma unroll
    for (int j = 0; j < 4; ++j) acc[i][j] = f32x4{0.f, 0.f, 0.f, 0.f};
  core128(ab, wout, m0, n0, L, acc);

  const int tid = threadIdx.x;
  const int lane = tid & 63, wave = tid >> 6;
  const int g = lane >> 4, q = lane & 15;
  const int wm = (wave >> 1) * 64, wn = (wave & 1) * 64;
  float* Lf = reinterpret_cast<float*>(L);    // 128x128 f32 = 64KB (core128 ended barrier'd)

  // write phase: swz col' = col ^ (bit2(row)<<2) ^ (bit3(row)<<4): 2-way max, float4-safe
  #pragma unroll
  for (int j = 0; j < 4; ++j) {
    int nc = wn + j * 16 + q;
    #pragma unroll
    for (int i = 0; i < 4; ++i) {
      #pragma unroll
      for (int rr = 0; rr < 4; ++rr) {
        int mr = wm + i * 16 + g * 4 + rr;
        int swz = ((mr & 4) << 0) | ((mr & 8) << 1);   // bits {2,4}
        Lf[mr * 128 + (nc ^ swz)] = acc[i][j][rr];
      }
    }
  }
  __syncthreads();

  // read+store phase: fully coalesced float4 stores + bf16 residual + bias
  #pragma unroll
  for (int k = 0; k < 16; ++k) {
    int ci = k * 256 + tid;          // 0..4095 = 128 rows x 32 col-chunks
    int row = ci >> 5, cb = (ci & 31) * 4;
    int swz = ((row & 4) << 0) | ((row & 8) << 1);
    float4 v = *(const float4*)(Lf + row * 128 + (cb ^ swz));
    size_t m = (size_t)(m0 + row);
    int n = n0 + cb;
    ushort4 xr = *(const ushort4*)(xbb + m * 1024 + n);
    float4 bv = *(const float4*)(bias + n);
    float4 o;
    o.x = v.x + bv.x + bf2f(xr.x);
    o.y = v.y + bv.y + bf2f(xr.y);
    o.z = v.z + bv.z + bf2f(xr.z);
    o.w = v.w + bv.w + bf2f(xr.w);
    *(float4*)(out + m * 1024 + n) = o;
  }
}

// ---------------- Flash attention v11: v5 body, NO setprio (compiler-free scheduling) --------
__device__ __forceinline__ void attn_step(const short8 kf[4][2], const short8 vf[2][4],
                                          const short8 qf[2][2], const short8 onesf,
                                          f32x4 oa[2][4], f32x4 la[2],
                                          ushort* pw0, int g, int q) {
  const f32x4 zed = {0.f, 0.f, 0.f, 0.f};
  #pragma unroll
  for (int t = 0; t < 2; ++t) {
    f32x4 sa[4];
    #pragma unroll
    for (int jt = 0; jt < 4; ++jt) {
      sa[jt] = MFMA16(kf[jt][0], qf[t][0], zed);
      sa[jt] = MFMA16(kf[jt][1], qf[t][1], sa[jt]);
    }
    ushort* pw = pw0 + t * 1152;
    #pragma unroll
    for (int jt = 0; jt < 4; ++jt) {
      uint2 wv;
      wv.x = cvtpk(hw_exp2(sa[jt][0]), hw_exp2(sa[jt][1]));
      wv.y = cvtpk(hw_exp2(sa[jt][2]), hw_exp2(sa[jt][3]));
      *reinterpret_cast<uint2*>(pw + q * 72 + jt * 16 + 4 * g) = wv;
    }
    #pragma unroll
    for (int jc = 0; jc < 2; ++jc) {
      short8 pa = *reinterpret_cast<const short8*>(pw + q * 72 + jc * 32 + g * 8);
      #pragma unroll
      for (int ct = 0; ct < 4; ++ct)
        oa[t][ct] = MFMA16(pa, vf[jc][ct], oa[t][ct]);
      la[t] = MFMA16(pa, onesf, la[t]);
    }
  }
}

__global__ __launch_bounds__(256) void attn_kernel(const ushort* __restrict__ QF, const ushort* __restrict__ KF,
                                                   const ushort* __restrict__ VF, ushort* __restrict__ aout) {
  __shared__ ushort Ps[4][2][16 * 72];
  // grid: 1024 1-D. Per XCD (bid&7): qb cycles fastest -> ~1-2 bh's K/V L2-hot.
  const int bid = blockIdx.x;
  const int xcd = bid & 7, rr = bid >> 3;
  const int qb = rr & 15, bh = xcd + (rr >> 4) * 8;
  const int lane = threadIdx.x & 63, wave = threadIdx.x >> 6;
  const int g = lane >> 4, q = lane & 15;
  const int qt0 = (qb * 4 + wave) * 2;
  const f32x4 zed = {0.f, 0.f, 0.f, 0.f};

  const ushort* Qb = QF + (size_t)bh * 131072 + lane * 8;
  const ushort* Kp = KF + (size_t)bh * 131072 + lane * 8;
  const ushort* Vp = VF + (size_t)bh * 131072 + lane * 8;
  ushort* pw0 = Ps[wave][0];

  short8 onesf;
  #pragma unroll
  for (int e = 0; e < 8; ++e) onesf[e] = (short)0x3F80;

  short8 qf[2][2];
  #pragma unroll
  for (int t = 0; t < 2; ++t)
    #pragma unroll
    for (int c0 = 0; c0 < 2; ++c0)
      qf[t][c0] = *(const short8*)(Qb + ((size_t)(qt0 + t) * 2 + c0) * 512);

  f32x4 oa[2][4], la[2];
  #pragma unroll
  for (int t = 0; t < 2; ++t) {
    la[t] = zed;
    #pragma unroll
    for (int ct = 0; ct < 4; ++ct) oa[t][ct] = zed;
  }

  short8 kfA[4][2], kfB[4][2], vfA[2][4], vfB[2][4];
  #pragma unroll
  for (int jt = 0; jt < 4; ++jt)
    #pragma unroll
    for (int c0 = 0; c0 < 2; ++c0)
      kfA[jt][c0] = *(const short8*)(Kp + ((size_t)jt * 2 + c0) * 512);

  #pragma unroll 1
  for (int i = 0; i < 32; i += 2) {
    #pragma unroll
    for (int jc = 0; jc < 2; ++jc)
      #pragma unroll
      for (int ct = 0; ct < 4; ++ct)
        vfA[jc][ct] = *(const short8*)(Vp + ((size_t)jc * 4 + ct) * 512);
    #pragma unroll
    for (int jt = 0; jt < 4; ++jt)
      #pragma unroll
      for (int c0 = 0; c0 < 2; ++c0)
        kfB[jt][c0] = *(const short8*)(Kp + 4096 + ((size_t)jt * 2 + c0) * 512);

    attn_step(kfA, vfA, qf, onesf, oa, la, pw0, g, q);

    #pragma unroll
    for (int jc = 0; jc < 2; ++jc)
      #pragma unroll
      for (int ct = 0; ct < 4; ++ct)
        vfB[jc][ct] = *(const short8*)(Vp + 4096 + ((size_t)jc * 4 + ct) * 512);
    if (i + 2 < 32) {
      #pragma unroll
      for (int jt = 0; jt < 4; ++jt)
        #pragma unroll
        for (int c0 = 0; c0 < 2; ++c0)
          kfA[jt][c0] = *(const short8*)(Kp + 8192 + ((size_t)jt * 2 + c0) * 512);
    }

    attn_step(kfB, vfB, qf, onesf, oa, la, pw0, g, q);

    Kp += 8192; Vp += 8192;
  }

  const int b = bh >> 4, h = bh & 15;
  #pragma unroll
  for (int t = 0; t < 2; ++t) {
    float inv[4];
    #pragma unroll
    for (int r2 = 0; r2 < 4; ++r2) inv[r2] = 1.0f / la[t][r2];
    #pragma unroll
    for (int ct = 0; ct < 4; ++ct) {
      size_t rowb = (size_t)b * SS + (qt0 + t) * 16 + 4 * g;
      int col = h * DD + ct * 16 + q;
      aout[(rowb + 0) * CC + col] = f2bf(oa[t][ct][0] * inv[0]);
      aout[(rowb + 1) * CC + col] = f2bf(oa[t][ct][1] * inv[1]);
      aout[(rowb + 2) * CC + col] = f2bf(oa[t][ct][2] * inv[2]);
      aout[(rowb + 3) * CC + col] = f2bf(oa[t][ct][3] * inv[3]);
    }
  }
}

extern "C" void kernel_launch(void* const* d_in, const int* in_sizes, int n_in,
                              void* d_out, int out_size, void* d_ws, size_t ws_size,
                              hipStream_t stream) {
  const float* x    = (const float*)d_in[0];   // [4,2048,1024]
  const float* wqkv = (const float*)d_in[1];   // [3072,1024]
  const float* wout = (const float*)d_in[2];   // [1024,1024]
  const float* bias = (const float*)d_in[3];   // [1024]
  float* out = (float*)d_out;

  // workspace carve (ushort elements), total 44M elems = 88MB
  ushort* xb    = (ushort*)d_ws;                   // 8M
  ushort* wqkvb = xb + (size_t)8 * 1024 * 1024;    // 3M
  ushort* woutb = wqkvb + (size_t)3 * 1024 * 1024; // 1M
  ushort* qfbuf = woutb + (size_t)1024 * 1024;     // 8M
  ushort* kfbuf = qfbuf + (size_t)8 * 1024 * 1024; // 8M
  ushort* vfbuf = kfbuf + (size_t)8 * 1024 * 1024; // 8M
  ushort* aout  = vfbuf + (size_t)8 * 1024 * 1024; // 8M

  hipLaunchKernelGGL(cvt3_kernel, dim3(2048), dim3(256), 0, stream,
                     x, xb, 8 * 1024 * 1024 / 4,
                     wqkv, wqkvb, 3 * 1024 * 1024 / 4,
                     wout, woutb, 1024 * 1024 / 4);

  hipLaunchKernelGGL(gemm_qkv, dim3(1536), dim3(256), 0, stream,
                     xb, wqkvb, qfbuf, kfbuf, vfbuf);
  hipLaunchKernelGGL(attn_kernel, dim3(1024), dim3(256), 0, stream,
                     qfbuf, kfbuf, vfbuf, aout);
  hipLaunchKernelGGL(gemm_out, dim3(512), dim3(256), 0, stream,
                     aout, woutb, xb, bias, out);
}